// Round 1
// baseline (134.468 us; speedup 1.0000x reference)
//
#include <hip/hip_runtime.h>
#include <math.h>

#define BS_ 16
#define NQ_ 900
#define NC_ 91
#define NT_ 1600
#define NROWS_ (BS_ * NQ_)

// One block per query row. 256 threads.
// Phase 1: softmax over 91 logits -> LDS prob table.
// Phase 2: each thread sweeps targets j = tid, tid+256, ... computing
//          C = 5*L1 + (-prob[id]) + 2*(-GIoU), coalesced row store.
__global__ __launch_bounds__(256) void matcher_cost_kernel(
    const float* __restrict__ logits,   // [NROWS_, NC_]
    const float* __restrict__ pboxes,   // [NROWS_, 4] cxcywh
    const float* __restrict__ tboxes,   // [NT_, 4]   cxcywh
    const int*   __restrict__ tids,     // [NT_]
    float* __restrict__ out)            // [NROWS_, NT_]
{
    const int row  = blockIdx.x;
    const int tid  = threadIdx.x;
    const int lane = tid & 63;
    const int wave = tid >> 6;

    __shared__ float sprob[NC_];
    __shared__ float sred[4];

    // ---- softmax over NC_=91 logits ----
    const float* lrow = logits + (size_t)row * NC_;
    float v = (tid < NC_) ? lrow[tid] : -INFINITY;

    // wave-level max (64 lanes)
    float m = v;
    #pragma unroll
    for (int off = 32; off >= 1; off >>= 1)
        m = fmaxf(m, __shfl_xor(m, off, 64));
    if (lane == 0) sred[wave] = m;
    __syncthreads();
    m = fmaxf(fmaxf(sred[0], sred[1]), fmaxf(sred[2], sred[3]));

    float e = (tid < NC_) ? __expf(v - m) : 0.0f;
    float s = e;
    #pragma unroll
    for (int off = 32; off >= 1; off >>= 1)
        s += __shfl_xor(s, off, 64);
    __syncthreads();              // all reads of sred (max) complete before reuse
    if (lane == 0) sred[wave] = s;
    __syncthreads();
    s = sred[0] + sred[1] + sred[2] + sred[3];
    const float inv_s = 1.0f / s;
    if (tid < NC_) sprob[tid] = e * inv_s;
    __syncthreads();

    // ---- query box (broadcast load) ----
    const float4 qb = *reinterpret_cast<const float4*>(pboxes + (size_t)row * 4);
    const float qx0 = qb.x - 0.5f * qb.z, qy0 = qb.y - 0.5f * qb.w;
    const float qx1 = qb.x + 0.5f * qb.z, qy1 = qb.y + 0.5f * qb.w;
    const float qarea = qb.z * qb.w;

    float* orow = out + (size_t)row * NT_;

    // ---- sweep targets ----
    for (int j = tid; j < NT_; j += 256) {
        const float4 tb = *reinterpret_cast<const float4*>(tboxes + (size_t)j * 4);
        const int id = tids[j];

        // L1 in cxcywh space
        const float cb = fabsf(qb.x - tb.x) + fabsf(qb.y - tb.y)
                       + fabsf(qb.z - tb.z) + fabsf(qb.w - tb.w);

        // target xyxy
        const float tx0 = tb.x - 0.5f * tb.z, ty0 = tb.y - 0.5f * tb.w;
        const float tx1 = tb.x + 0.5f * tb.z, ty1 = tb.y + 0.5f * tb.w;
        const float tarea = tb.z * tb.w;

        // intersection
        float iw = fminf(qx1, tx1) - fmaxf(qx0, tx0);
        float ih = fminf(qy1, ty1) - fmaxf(qy0, ty0);
        iw = fmaxf(iw, 0.0f);
        ih = fmaxf(ih, 0.0f);
        const float inter = iw * ih;
        const float uni   = qarea + tarea - inter;
        const float iou   = inter / uni;

        // smallest enclosing box
        const float cw = fmaxf(qx1, tx1) - fminf(qx0, tx0);
        const float ch = fmaxf(qy1, ty1) - fminf(qy0, ty0);
        const float areac = fmaxf(cw, 0.0f) * fmaxf(ch, 0.0f);
        const float giou  = iou - (areac - uni) / areac;

        // C = 5*L1 + 1*(-p) + 2*(-giou)
        orow[j] = 5.0f * cb - sprob[id] - 2.0f * giou;
    }
}

extern "C" void kernel_launch(void* const* d_in, const int* in_sizes, int n_in,
                              void* d_out, int out_size, void* d_ws, size_t ws_size,
                              hipStream_t stream) {
    const float* logits = (const float*)d_in[0];  // [16,900,91]
    const float* pboxes = (const float*)d_in[1];  // [16,900,4]
    const float* tboxes = (const float*)d_in[2];  // [1600,4]
    const int*   tids   = (const int*)d_in[3];    // [1600]
    float* out = (float*)d_out;                   // [16,900,1600]

    matcher_cost_kernel<<<NROWS_, 256, 0, stream>>>(logits, pboxes, tboxes, tids, out);
}

// Round 2
// 127.357 us; speedup vs baseline: 1.0558x; 1.0558x over previous
//
#include <hip/hip_runtime.h>
#include <math.h>

#define BS_ 16
#define NQ_ 900
#define NC_ 91
#define NT_ 1600
#define NROWS_ (BS_ * NQ_)
#define NT4_ (NT_ / 4)   // 400 float4 outputs per row

// Per-pair cost:
//   giou = iou - (areac - uni)/areac = iou - 1 + uni/areac
//   C    = 5*L1 - p - 2*giou = 5*L1 - p + 2 - 2*inter*rcp(uni) - 2*uni*rcp(areac)
// v_rcp_f32 (~1 ulp) replaces the ~12-instruction IEEE divide sequence; error
// ~1e-7 relative vs bf16-scale threshold 0.365.
__device__ __forceinline__ float pair_cost(
    float qcx, float qcy, float qw, float qh,
    float qx0, float qy0, float qx1, float qy1, float qarea,
    float4 tb, float p)
{
    // L1 in cxcywh space
    const float cb = fabsf(qcx - tb.x) + fabsf(qcy - tb.y)
                   + fabsf(qw  - tb.z) + fabsf(qh  - tb.w);

    // target xyxy (fma)
    const float tx0 = fmaf(-0.5f, tb.z, tb.x);
    const float ty0 = fmaf(-0.5f, tb.w, tb.y);
    const float tx1 = fmaf( 0.5f, tb.z, tb.x);
    const float ty1 = fmaf( 0.5f, tb.w, tb.y);
    const float tarea = tb.z * tb.w;

    const float iw = fmaxf(fminf(qx1, tx1) - fmaxf(qx0, tx0), 0.0f);
    const float ih = fmaxf(fminf(qy1, ty1) - fmaxf(qy0, ty0), 0.0f);
    const float inter = iw * ih;
    const float uni   = qarea + tarea - inter;

    // enclosing box: max-min >= 0 always, no clamp needed
    const float cw = fmaxf(qx1, tx1) - fminf(qx0, tx0);
    const float ch = fmaxf(qy1, ty1) - fminf(qy0, ty0);
    const float areac = cw * ch;

    const float r1 = __builtin_amdgcn_rcpf(uni);
    const float r2 = __builtin_amdgcn_rcpf(areac);

    float c = fmaf(5.0f, cb, 2.0f - p);
    c = fmaf(-2.0f * inter, r1, c);
    c = fmaf(-2.0f * uni,   r2, c);
    return c;
}

__global__ __launch_bounds__(256) void matcher_cost_kernel(
    const float* __restrict__ logits,    // [NROWS_, NC_]
    const float* __restrict__ pboxes,    // [NROWS_, 4] cxcywh
    const float4* __restrict__ tboxes,   // [NT_] cxcywh
    const int4*  __restrict__ tids,      // [NT4_]
    float4* __restrict__ out)            // [NROWS_, NT4_]
{
    const int row  = blockIdx.x;
    const int tid  = threadIdx.x;
    const int lane = tid & 63;
    const int wave = tid >> 6;

    __shared__ float sprob[NC_];
    __shared__ float sred[4];

    // ---- softmax over NC_=91 logits ----
    const float* lrow = logits + (size_t)row * NC_;
    float v = (tid < NC_) ? lrow[tid] : -INFINITY;

    float m = v;
    #pragma unroll
    for (int off = 32; off >= 1; off >>= 1)
        m = fmaxf(m, __shfl_xor(m, off, 64));
    if (lane == 0) sred[wave] = m;
    __syncthreads();
    m = fmaxf(fmaxf(sred[0], sred[1]), fmaxf(sred[2], sred[3]));

    float e = (tid < NC_) ? __expf(v - m) : 0.0f;
    float s = e;
    #pragma unroll
    for (int off = 32; off >= 1; off >>= 1)
        s += __shfl_xor(s, off, 64);
    __syncthreads();
    if (lane == 0) sred[wave] = s;
    __syncthreads();
    s = sred[0] + sred[1] + sred[2] + sred[3];
    const float inv_s = __builtin_amdgcn_rcpf(s);
    if (tid < NC_) sprob[tid] = e * inv_s;
    __syncthreads();

    // ---- query box (broadcast load, row-invariant) ----
    const float4 qb = *reinterpret_cast<const float4*>(pboxes + (size_t)row * 4);
    const float qx0 = fmaf(-0.5f, qb.z, qb.x);
    const float qy0 = fmaf(-0.5f, qb.w, qb.y);
    const float qx1 = fmaf( 0.5f, qb.z, qb.x);
    const float qy1 = fmaf( 0.5f, qb.w, qb.y);
    const float qarea = qb.z * qb.w;

    float4* orow = out + (size_t)row * NT4_;

    // ---- sweep targets, 4 per thread per pass (2 passes: 256 + 144) ----
    #pragma unroll
    for (int p = 0; p < 2; ++p) {
        const int v4 = p * 256 + tid;          // float4 index in row
        if (v4 < NT4_) {
            const int j = v4 * 4;
            const int4  id4 = tids[v4];
            const float4 t0 = tboxes[j + 0];
            const float4 t1 = tboxes[j + 1];
            const float4 t2 = tboxes[j + 2];
            const float4 t3 = tboxes[j + 3];

            float4 r;
            r.x = pair_cost(qb.x, qb.y, qb.z, qb.w, qx0, qy0, qx1, qy1, qarea, t0, sprob[id4.x]);
            r.y = pair_cost(qb.x, qb.y, qb.z, qb.w, qx0, qy0, qx1, qy1, qarea, t1, sprob[id4.y]);
            r.z = pair_cost(qb.x, qb.y, qb.z, qb.w, qx0, qy0, qx1, qy1, qarea, t2, sprob[id4.z]);
            r.w = pair_cost(qb.x, qb.y, qb.z, qb.w, qx0, qy0, qx1, qy1, qarea, t3, sprob[id4.w]);
            orow[v4] = r;
        }
    }
}

extern "C" void kernel_launch(void* const* d_in, const int* in_sizes, int n_in,
                              void* d_out, int out_size, void* d_ws, size_t ws_size,
                              hipStream_t stream) {
    const float*  logits = (const float*)d_in[0];   // [16,900,91]
    const float*  pboxes = (const float*)d_in[1];   // [16,900,4]
    const float4* tboxes = (const float4*)d_in[2];  // [1600,4]
    const int4*   tids   = (const int4*)d_in[3];    // [1600]
    float4* out = (float4*)d_out;                   // [16,900,1600]

    matcher_cost_kernel<<<NROWS_, 256, 0, stream>>>(logits, pboxes, tboxes, tids, out);
}

// Round 3
// 119.976 us; speedup vs baseline: 1.1208x; 1.0615x over previous
//
#include <hip/hip_runtime.h>
#include <math.h>

#define BS_ 16
#define NQ_ 900
#define NC_ 91
#define NT_ 1600
#define NROWS_ (BS_ * NQ_)
#define TILE_R 4
#define NBLK (NROWS_ / TILE_R)   // 3600 blocks

// One block = TILE_R=4 consecutive query rows, 256 threads (4 waves).
// Wave w computes softmax for row base+w (91 classes, shuffle reduction),
// storing probs TRANSPOSED in LDS: sprob_t[id][row] so the per-target
// gather is a single ds_read_b128 covering all 4 rows.
// Then threads sweep j = tid..1600 step 256; per j: one float4 tbox load +
// xyxy precompute (amortized over 4 rows), then 4 pair costs + 4 coalesced
// nontemporal dword stores.
__global__ __launch_bounds__(256) void matcher_cost_kernel(
    const float* __restrict__ logits,    // [NROWS_, NC_]
    const float* __restrict__ pboxes,    // [NROWS_, 4] cxcywh
    const float4* __restrict__ tboxes,   // [NT_] cxcywh
    const int*   __restrict__ tids,      // [NT_]
    float* __restrict__ out)             // [NROWS_, NT_]
{
    const int base = blockIdx.x * TILE_R;
    const int tid  = threadIdx.x;
    const int lane = tid & 63;
    const int wave = tid >> 6;

    __shared__ __align__(16) float sprob_t[NC_ * TILE_R];  // [id][row]

    // ---- softmax: wave w handles row base+w ----
    {
        const float* lrow = logits + (size_t)(base + wave) * NC_;
        float v0 = lrow[lane];                               // lanes 0..63 all < 91
        float v1 = (lane < NC_ - 64) ? lrow[64 + lane] : -INFINITY;
        float m = fmaxf(v0, v1);
        #pragma unroll
        for (int off = 32; off >= 1; off >>= 1)
            m = fmaxf(m, __shfl_xor(m, off, 64));
        float e0 = __expf(v0 - m);
        float e1 = (lane < NC_ - 64) ? __expf(v1 - m) : 0.0f;
        float s = e0 + e1;
        #pragma unroll
        for (int off = 32; off >= 1; off >>= 1)
            s += __shfl_xor(s, off, 64);
        const float inv_s = __builtin_amdgcn_rcpf(s);
        sprob_t[lane * TILE_R + wave] = e0 * inv_s;
        if (lane < NC_ - 64)
            sprob_t[(64 + lane) * TILE_R + wave] = e1 * inv_s;
    }
    __syncthreads();

    // ---- row constants (block-uniform addresses -> scalar loads) ----
    float qcx[TILE_R], qcy[TILE_R], qw[TILE_R], qh[TILE_R];
    float qx0[TILE_R], qy0[TILE_R], qx1[TILE_R], qy1[TILE_R], qarea[TILE_R];
    #pragma unroll
    for (int r = 0; r < TILE_R; ++r) {
        const float4 qb = *reinterpret_cast<const float4*>(pboxes + (size_t)(base + r) * 4);
        qcx[r] = qb.x; qcy[r] = qb.y; qw[r] = qb.z; qh[r] = qb.w;
        qx0[r] = fmaf(-0.5f, qb.z, qb.x);
        qy0[r] = fmaf(-0.5f, qb.w, qb.y);
        qx1[r] = fmaf( 0.5f, qb.z, qb.x);
        qy1[r] = fmaf( 0.5f, qb.w, qb.y);
        qarea[r] = qb.z * qb.w;
    }

    // ---- target sweep: 7 iterations (6 full + 64 lanes) ----
    for (int j = tid; j < NT_; j += 256) {
        const float4 tb = tboxes[j];
        const int id = tids[j];

        const float tx0 = fmaf(-0.5f, tb.z, tb.x);
        const float ty0 = fmaf(-0.5f, tb.w, tb.y);
        const float tx1 = fmaf( 0.5f, tb.z, tb.x);
        const float ty1 = fmaf( 0.5f, tb.w, tb.y);
        const float tarea = tb.z * tb.w;

        const float4 p4 = *reinterpret_cast<const float4*>(&sprob_t[id * TILE_R]);
        const float p[TILE_R] = {p4.x, p4.y, p4.z, p4.w};

        #pragma unroll
        for (int r = 0; r < TILE_R; ++r) {
            const float cb = fabsf(qcx[r] - tb.x) + fabsf(qcy[r] - tb.y)
                           + fabsf(qw[r]  - tb.z) + fabsf(qh[r]  - tb.w);

            const float iw = fmaxf(fminf(qx1[r], tx1) - fmaxf(qx0[r], tx0), 0.0f);
            const float ih = fmaxf(fminf(qy1[r], ty1) - fmaxf(qy0[r], ty0), 0.0f);
            const float inter = iw * ih;
            const float uni   = qarea[r] + tarea - inter;

            const float cw = fmaxf(qx1[r], tx1) - fminf(qx0[r], tx0);
            const float ch = fmaxf(qy1[r], ty1) - fminf(qy0[r], ty0);
            const float areac = cw * ch;

            // C = 5*L1 - p + 2 - 2*inter/uni - 2*uni/areac
            float c = fmaf(5.0f, cb, 2.0f - p[r]);
            c = fmaf(-2.0f * inter, __builtin_amdgcn_rcpf(uni),   c);
            c = fmaf(-2.0f * uni,   __builtin_amdgcn_rcpf(areac), c);

            __builtin_nontemporal_store(c, out + (size_t)(base + r) * NT_ + j);
        }
    }
}

extern "C" void kernel_launch(void* const* d_in, const int* in_sizes, int n_in,
                              void* d_out, int out_size, void* d_ws, size_t ws_size,
                              hipStream_t stream) {
    const float*  logits = (const float*)d_in[0];   // [16,900,91]
    const float*  pboxes = (const float*)d_in[1];   // [16,900,4]
    const float4* tboxes = (const float4*)d_in[2];  // [1600,4]
    const int*    tids   = (const int*)d_in[3];     // [1600]
    float* out = (float*)d_out;                     // [16,900,1600]

    matcher_cost_kernel<<<NBLK, 256, 0, stream>>>(logits, pboxes, tboxes, tids, out);
}

// Round 4
// 118.947 us; speedup vs baseline: 1.1305x; 1.0087x over previous
//
#include <hip/hip_runtime.h>
#include <math.h>

#define BS_ 16
#define NQ_ 900
#define NC_ 91
#define NT_ 1600
#define NROWS_ (BS_ * NQ_)
#define TILE_R 4
#define TPB 320                  // 5 waves; 1600/320 = 5 uniform iterations
#define NBLK (NROWS_ / TILE_R)   // 3600 blocks
#define KITER (NT_ / TPB)        // 5

// Block = 4 query rows, 320 threads. Waves 0-3: softmax of one row each,
// storing (2 - prob) transposed in LDS so the per-target gather is one
// ds_read_b128 covering all 4 rows AND folds the "+2-p" epilogue term.
// Sweep: 5 uniform iterations, fully unrolled, loads batched ahead of
// compute. Enclosing box via cw = (qw+tw) - dx (dx = unclamped overlap).
__global__ __launch_bounds__(TPB) void matcher_cost_kernel(
    const float* __restrict__ logits,    // [NROWS_, NC_]
    const float* __restrict__ pboxes,    // [NROWS_, 4] cxcywh
    const float4* __restrict__ tboxes,   // [NT_] cxcywh
    const int*   __restrict__ tids,      // [NT_]
    float* __restrict__ out)             // [NROWS_, NT_]
{
    const int base = blockIdx.x * TILE_R;
    const int tid  = threadIdx.x;
    const int lane = tid & 63;
    const int wave = tid >> 6;

    __shared__ __align__(16) float sneg[NC_ * TILE_R];  // (2 - p)[id][row]

    // ---- softmax: waves 0..3, one row each; wave 4 skips ----
    if (wave < TILE_R) {
        const float* lrow = logits + (base + wave) * NC_;
        float v0 = lrow[lane];
        float v1 = (lane < NC_ - 64) ? lrow[64 + lane] : -INFINITY;
        float m = fmaxf(v0, v1);
        #pragma unroll
        for (int off = 32; off >= 1; off >>= 1)
            m = fmaxf(m, __shfl_xor(m, off, 64));
        float e0 = __expf(v0 - m);
        float e1 = (lane < NC_ - 64) ? __expf(v1 - m) : 0.0f;
        float s = e0 + e1;
        #pragma unroll
        for (int off = 32; off >= 1; off >>= 1)
            s += __shfl_xor(s, off, 64);
        const float inv_s = __builtin_amdgcn_rcpf(s);
        sneg[lane * TILE_R + wave] = fmaf(-e0, inv_s, 2.0f);
        if (lane < NC_ - 64)
            sneg[(64 + lane) * TILE_R + wave] = fmaf(-e1, inv_s, 2.0f);
    }

    // ---- batch global prefetch (independent of LDS; issued pre-barrier) ----
    float4 tb[KITER];
    int    id[KITER];
    #pragma unroll
    for (int k = 0; k < KITER; ++k) {
        const int j = k * TPB + tid;
        tb[k] = tboxes[j];
        id[k] = tids[j];
    }

    // ---- row constants (block-uniform addresses) ----
    float qcx[TILE_R], qcy[TILE_R], qw[TILE_R], qh[TILE_R];
    float qx0[TILE_R], qy0[TILE_R], qx1[TILE_R], qy1[TILE_R], qarea[TILE_R];
    #pragma unroll
    for (int r = 0; r < TILE_R; ++r) {
        const float4 qb = *reinterpret_cast<const float4*>(pboxes + (base + r) * 4);
        qcx[r] = qb.x; qcy[r] = qb.y; qw[r] = qb.z; qh[r] = qb.w;
        qx0[r] = fmaf(-0.5f, qb.z, qb.x);
        qy0[r] = fmaf(-0.5f, qb.w, qb.y);
        qx1[r] = fmaf( 0.5f, qb.z, qb.x);
        qy1[r] = fmaf( 0.5f, qb.w, qb.y);
        qarea[r] = qb.z * qb.w;
    }

    __syncthreads();

    // ---- batch prob gathers (one b128 per k serves all 4 rows) ----
    float4 pp[KITER];
    #pragma unroll
    for (int k = 0; k < KITER; ++k)
        pp[k] = *reinterpret_cast<const float4*>(&sneg[id[k] * TILE_R]);

    // ---- straight-line compute + store ----
    #pragma unroll
    for (int k = 0; k < KITER; ++k) {
        const int j = k * TPB + tid;
        const float4 t = tb[k];
        const float tx0 = fmaf(-0.5f, t.z, t.x);
        const float ty0 = fmaf(-0.5f, t.w, t.y);
        const float tx1 = fmaf( 0.5f, t.z, t.x);
        const float ty1 = fmaf( 0.5f, t.w, t.y);
        const float tarea = t.z * t.w;
        const float p[TILE_R] = {pp[k].x, pp[k].y, pp[k].z, pp[k].w};

        #pragma unroll
        for (int r = 0; r < TILE_R; ++r) {
            const float cb = fabsf(qcx[r] - t.x) + fabsf(qcy[r] - t.y)
                           + fabsf(qw[r]  - t.z) + fabsf(qh[r]  - t.w);

            // unclamped overlap extents
            const float dx = fminf(qx1[r], tx1) - fmaxf(qx0[r], tx0);
            const float dy = fminf(qy1[r], ty1) - fmaxf(qy0[r], ty0);
            const float inter = fmaxf(dx, 0.0f) * fmaxf(dy, 0.0f);
            const float uni   = (qarea[r] + tarea) - inter;

            // enclosing box via identity: cw + dx = qw + tw
            const float cw = (qw[r] + t.z) - dx;
            const float ch = (qh[r] + t.w) - dy;
            const float areac = cw * ch;

            // C = 5*L1 + (2 - p) - 2*inter/uni - 2*uni/areac
            float c = fmaf(5.0f, cb, p[r]);
            c = fmaf(-2.0f * inter, __builtin_amdgcn_rcpf(uni),   c);
            c = fmaf(-2.0f * uni,   __builtin_amdgcn_rcpf(areac), c);

            __builtin_nontemporal_store(c, out + (base + r) * NT_ + j);
        }
    }
}

extern "C" void kernel_launch(void* const* d_in, const int* in_sizes, int n_in,
                              void* d_out, int out_size, void* d_ws, size_t ws_size,
                              hipStream_t stream) {
    const float*  logits = (const float*)d_in[0];   // [16,900,91]
    const float*  pboxes = (const float*)d_in[1];   // [16,900,4]
    const float4* tboxes = (const float4*)d_in[2];  // [1600,4]
    const int*    tids   = (const int*)d_in[3];     // [1600]
    float* out = (float*)d_out;                     // [16,900,1600]

    matcher_cost_kernel<<<NBLK, TPB, 0, stream>>>(logits, pboxes, tboxes, tids, out);
}